// Round 1
// baseline (393.904 us; speedup 1.0000x reference)
//
#include <hip/hip_runtime.h>

#define NB 2
#define NS 2048
#define NDM 1024
#define NH 16
#define NDK 64

typedef unsigned int u32;
typedef u32 u32x4 __attribute__((ext_vector_type(4)));
typedef float f32x4 __attribute__((ext_vector_type(4)));
typedef __bf16 bf16x8 __attribute__((ext_vector_type(8)));
typedef __bf16 bf16x4 __attribute__((ext_vector_type(4)));
typedef __bf16 bf16x2 __attribute__((ext_vector_type(2)));

// ---------------- fp32 -> bf16 cast (vectorized) ----------------
__global__ __launch_bounds__(256) void cvt_f32_bf16(const float* __restrict__ src,
                                                    __bf16* __restrict__ dst, int n4) {
    int i = blockIdx.x * blockDim.x + threadIdx.x;
    if (i >= n4) return;
    f32x4 v = *(const f32x4*)(src + (size_t)i * 4);
    bf16x4 o;
    o[0] = (__bf16)v[0]; o[1] = (__bf16)v[1]; o[2] = (__bf16)v[2]; o[3] = (__bf16)v[3];
    *(bf16x4*)(dst + (size_t)i * 4) = o;
}

// ---------------- GEMM: C[M,N] = A[M,K] * Bt[N,K]^T ----------------
// 64x64 block tile, 4 waves (2x2), each wave 32x32, BK=64, mfma 16x16x32 bf16.
__global__ __launch_bounds__(256) void gemm_bt(const __bf16* __restrict__ A,
                                               const __bf16* __restrict__ Bt,
                                               float* __restrict__ C,
                                               int M, int N, int K,
                                               int lda, int ldb, int ldc) {
    __shared__ __bf16 As[64 * 72];  // row stride 72 (=144B) -> 2-way bank alias only
    __shared__ __bf16 Bs[64 * 72];
    const int tid = threadIdx.x;
    const int lane = tid & 63, w = tid >> 6;
    const int wr = w >> 1, wc = w & 1;
    const int l15 = lane & 15, lg = lane >> 4;
    const int m0 = blockIdx.y * 64, n0 = blockIdx.x * 64;
    const int lr = tid >> 3, lc = (tid & 7) * 8;

    f32x4 acc[2][2];
    const f32x4 z = {0.f, 0.f, 0.f, 0.f};
    acc[0][0] = z; acc[0][1] = z; acc[1][0] = z; acc[1][1] = z;

    for (int k0 = 0; k0 < K; k0 += 64) {
        __syncthreads();
        *(u32x4*)&As[lr * 72 + lc]        = *(const u32x4*)&A[(size_t)(m0 + lr) * lda + k0 + lc];
        *(u32x4*)&As[(lr + 32) * 72 + lc] = *(const u32x4*)&A[(size_t)(m0 + lr + 32) * lda + k0 + lc];
        *(u32x4*)&Bs[lr * 72 + lc]        = *(const u32x4*)&Bt[(size_t)(n0 + lr) * ldb + k0 + lc];
        *(u32x4*)&Bs[(lr + 32) * 72 + lc] = *(const u32x4*)&Bt[(size_t)(n0 + lr + 32) * ldb + k0 + lc];
        __syncthreads();
#pragma unroll
        for (int kc = 0; kc < 2; ++kc) {
            bf16x8 af[2], bfr[2];
            af[0]  = *(const bf16x8*)&As[(wr * 32 + l15) * 72 + kc * 32 + lg * 8];
            af[1]  = *(const bf16x8*)&As[(wr * 32 + 16 + l15) * 72 + kc * 32 + lg * 8];
            bfr[0] = *(const bf16x8*)&Bs[(wc * 32 + l15) * 72 + kc * 32 + lg * 8];
            bfr[1] = *(const bf16x8*)&Bs[(wc * 32 + 16 + l15) * 72 + kc * 32 + lg * 8];
#pragma unroll
            for (int sm = 0; sm < 2; ++sm)
#pragma unroll
                for (int sn = 0; sn < 2; ++sn)
                    acc[sm][sn] = __builtin_amdgcn_mfma_f32_16x16x32_bf16(af[sm], bfr[sn], acc[sm][sn], 0, 0, 0);
        }
    }
#pragma unroll
    for (int sm = 0; sm < 2; ++sm)
#pragma unroll
        for (int sn = 0; sn < 2; ++sn)
#pragma unroll
            for (int j = 0; j < 4; ++j) {
                int row = m0 + wr * 32 + sm * 16 + lg * 4 + j;
                int col = n0 + wc * 32 + sn * 16 + l15;
                C[(size_t)row * ldc + col] = acc[sm][sn][j];
            }
}

// ---------------- RoPE on Q and K halves of the projection ----------------
// qkv: [B*S, 3072] fp32 (cols 0..1023 Q, 1024..2047 K, 2048..3071 V)
// Qr/Kr: [B*H, S, 64] bf16, rotated.
__global__ __launch_bounds__(512) void rope_kernel(const float* __restrict__ qkv,
                                                   const int* __restrict__ tp,
                                                   __bf16* __restrict__ Qr,
                                                   __bf16* __restrict__ Kr) {
    const int row = blockIdx.x;           // b*S + s
    const int s = row & (NS - 1);
    const int b = row >> 11;
    const int t = threadIdx.x;            // 512 threads = 512 pairs
    const int h = t >> 5, jj = t & 31;
    const float pos = (float)tp[s];
    const float inv = powf(10000.0f, -(float)jj * (1.0f / 32.0f));
    const float ang = pos * inv;
    float sn, cs;
    sincosf(ang, &sn, &cs);
    const float* qp = qkv + (size_t)row * 3072 + h * 64 + 2 * jj;
    const float q0 = qp[0], q1 = qp[1];
    const float k0 = qp[1024], k1 = qp[1025];
    const size_t o = ((size_t)(b * NH + h) * NS + s) * 64 + 2 * jj;
    bf16x2 qo, ko;
    qo[0] = (__bf16)(q0 * cs - q1 * sn); qo[1] = (__bf16)(q0 * sn + q1 * cs);
    ko[0] = (__bf16)(k0 * cs - k1 * sn); ko[1] = (__bf16)(k0 * sn + k1 * cs);
    *(bf16x2*)&Qr[o] = qo;
    *(bf16x2*)&Kr[o] = ko;
}

// ---------------- V transpose: qkv V-part -> Vt [B*H, 64, S] bf16 ----------------
__global__ __launch_bounds__(256) void vtrans(const float* __restrict__ qkv,
                                              __bf16* __restrict__ Vt) {
    const int bh = blockIdx.y;
    const int s0 = blockIdx.x * 64;
    const int b = bh >> 4, h = bh & 15;
    __shared__ float tile[64][65];
    const int t = threadIdx.x;
    const int sl = t >> 4, d4 = (t & 15) * 4;
#pragma unroll
    for (int i = 0; i < 4; ++i) {
        f32x4 v = *(const f32x4*)&qkv[(size_t)(b * NS + s0 + sl + i * 16) * 3072 + 2048 + h * 64 + d4];
        tile[sl + i * 16][d4 + 0] = v[0];
        tile[sl + i * 16][d4 + 1] = v[1];
        tile[sl + i * 16][d4 + 2] = v[2];
        tile[sl + i * 16][d4 + 3] = v[3];
    }
    __syncthreads();
    const int d = t >> 3, sl2 = (t & 7) * 8;
#pragma unroll
    for (int p = 0; p < 2; ++p) {
        const int dd = d + p * 32;
        bf16x8 o;
#pragma unroll
        for (int i = 0; i < 8; ++i) o[i] = (__bf16)tile[sl2 + i][dd];
        *(bf16x8*)&Vt[((size_t)bh * 64 + dd) * NS + s0 + sl2] = o;
    }
}

// ---------------- causal flash attention ----------------
// grid: (S/64, B*H); 256 threads = 4 waves, each wave owns 16 q rows.
// Qr/Kr [bh][S][64], Vt [bh][64][S]; O [B,S,1024] bf16 (head h -> cols h*64..h*64+63)
__global__ __launch_bounds__(256) void attn_kernel(const __bf16* __restrict__ Qr,
                                                   const __bf16* __restrict__ Kr,
                                                   const __bf16* __restrict__ Vt,
                                                   __bf16* __restrict__ O) {
    const int bh = blockIdx.y;
    const int b = bh >> 4, h = bh & 15;
    const int q0 = blockIdx.x * 64;
    const int tid = threadIdx.x;
    const int w = tid >> 6, lane = tid & 63;
    const int l15 = lane & 15, lg = lane >> 4;
    const __bf16* Qbase = Qr + (size_t)bh * NS * 64;
    const __bf16* Kbase = Kr + (size_t)bh * NS * 64;
    const __bf16* Vbase = Vt + (size_t)bh * 64 * NS;

    __shared__ __bf16 Plds[4][16][72];

    const int qrow = q0 + w * 16 + l15;  // A-fragment row for this lane
    bf16x8 qf[2];
#pragma unroll
    for (int kc = 0; kc < 2; ++kc)
        qf[kc] = *(const bf16x8*)(Qbase + (size_t)qrow * 64 + kc * 32 + lg * 8);

    const f32x4 z = {0.f, 0.f, 0.f, 0.f};
    f32x4 oacc[4];
#pragma unroll
    for (int ct = 0; ct < 4; ++ct) oacc[ct] = z;
    float m[4], lsum[4];
#pragma unroll
    for (int j = 0; j < 4; ++j) { m[j] = -__builtin_inff(); lsum[j] = 0.f; }

    for (int kv0 = 0; kv0 <= q0; kv0 += 64) {
        // ---- scores: 16 q-rows x 64 k-cols ----
        f32x4 sc[4];
#pragma unroll
        for (int ct = 0; ct < 4; ++ct) sc[ct] = z;
#pragma unroll
        for (int ct = 0; ct < 4; ++ct)
#pragma unroll
            for (int kc = 0; kc < 2; ++kc) {
                bf16x8 kf = *(const bf16x8*)(Kbase + (size_t)(kv0 + ct * 16 + l15) * 64 + kc * 32 + lg * 8);
                sc[ct] = __builtin_amdgcn_mfma_f32_16x16x32_bf16(qf[kc], kf, sc[ct], 0, 0, 0);
            }
        // ---- scale + causal mask ----
#pragma unroll
        for (int ct = 0; ct < 4; ++ct)
#pragma unroll
            for (int j = 0; j < 4; ++j) {
                const int col = kv0 + ct * 16 + l15;
                const int rw = q0 + w * 16 + lg * 4 + j;
                float sv = sc[ct][j] * 0.125f;
                sc[ct][j] = (col <= rw) ? sv : -__builtin_inff();
            }
        // ---- online softmax (row stats across 16 lanes of each group) ----
        float alpha[4];
#pragma unroll
        for (int j = 0; j < 4; ++j) {
            float mt = fmaxf(fmaxf(sc[0][j], sc[1][j]), fmaxf(sc[2][j], sc[3][j]));
#pragma unroll
            for (int d = 1; d < 16; d <<= 1) mt = fmaxf(mt, __shfl_xor(mt, d, 64));
            const float mn = fmaxf(m[j], mt);
            const float al = __expf(m[j] - mn);
            m[j] = mn;
            float ps = 0.f;
#pragma unroll
            for (int ct = 0; ct < 4; ++ct) {
                const float p = __expf(sc[ct][j] - mn);
                sc[ct][j] = p;
                ps += p;
            }
#pragma unroll
            for (int d = 1; d < 16; d <<= 1) ps += __shfl_xor(ps, d, 64);
            lsum[j] = lsum[j] * al + ps;
            alpha[j] = al;
        }
#pragma unroll
        for (int ct = 0; ct < 4; ++ct)
#pragma unroll
            for (int j = 0; j < 4; ++j) oacc[ct][j] *= alpha[j];

        // ---- P -> LDS (bf16), row r = lg*4+j, col = ct*16+l15 ----
#pragma unroll
        for (int ct = 0; ct < 4; ++ct)
#pragma unroll
            for (int j = 0; j < 4; ++j)
                Plds[w][lg * 4 + j][ct * 16 + l15] = (__bf16)sc[ct][j];
        __syncthreads();

        // ---- PV: O[16 q][64 v] += P[16][64] * V[64][64v] ----
#pragma unroll
        for (int kc = 0; kc < 2; ++kc) {
            bf16x8 pf = *(const bf16x8*)&Plds[w][l15][kc * 32 + lg * 8];
#pragma unroll
            for (int ct = 0; ct < 4; ++ct) {
                bf16x8 vf = *(const bf16x8*)(Vbase + (size_t)(ct * 16 + l15) * NS + kv0 + kc * 32 + lg * 8);
                oacc[ct] = __builtin_amdgcn_mfma_f32_16x16x32_bf16(pf, vf, oacc[ct], 0, 0, 0);
            }
        }
        __syncthreads();
    }

    // ---- epilogue ----
#pragma unroll
    for (int ct = 0; ct < 4; ++ct)
#pragma unroll
        for (int j = 0; j < 4; ++j) {
            const int rw = q0 + w * 16 + lg * 4 + j;
            const float val = oacc[ct][j] / lsum[j];
            O[(size_t)(b * NS + rw) * NDM + h * 64 + ct * 16 + l15] = (__bf16)val;
        }
}

// ---------------- launch ----------------
extern "C" void kernel_launch(void* const* d_in, const int* in_sizes, int n_in,
                              void* d_out, int out_size, void* d_ws, size_t ws_size,
                              hipStream_t stream) {
    const float* x  = (const float*)d_in[0];
    const float* Qw = (const float*)d_in[1];
    const float* Kw = (const float*)d_in[2];
    const float* Vw = (const float*)d_in[3];
    const float* Ow = (const float*)d_in[4];
    const int*   tp = (const int*)d_in[5];
    float* out = (float*)d_out;

    char* ws = (char*)d_ws;
    size_t off = 0;
    auto alloc = [&](size_t bytes) -> void* {
        void* p = ws + off;
        off += (bytes + 255) & ~(size_t)255;
        return p;
    };
    __bf16* xb   = (__bf16*)alloc((size_t)4096 * 1024 * 2);
    __bf16* wqkv = (__bf16*)alloc((size_t)3072 * 1024 * 2);
    __bf16* owb  = (__bf16*)alloc((size_t)1024 * 1024 * 2);
    float*  qkv  = (float*)alloc((size_t)4096 * 3072 * 4);
    __bf16* qr   = (__bf16*)alloc((size_t)32 * 2048 * 64 * 2);
    __bf16* kr   = (__bf16*)alloc((size_t)32 * 2048 * 64 * 2);
    __bf16* vt   = (__bf16*)alloc((size_t)32 * 64 * 2048 * 2);
    __bf16* ob   = (__bf16*)alloc((size_t)4096 * 1024 * 2);

    // casts
    cvt_f32_bf16<<<4096, 256, 0, stream>>>(x, xb, 4096 * 1024 / 4);
    cvt_f32_bf16<<<1024, 256, 0, stream>>>(Qw, wqkv, 1024 * 1024 / 4);
    cvt_f32_bf16<<<1024, 256, 0, stream>>>(Kw, wqkv + 1024 * 1024, 1024 * 1024 / 4);
    cvt_f32_bf16<<<1024, 256, 0, stream>>>(Vw, wqkv + 2048 * 1024, 1024 * 1024 / 4);
    cvt_f32_bf16<<<1024, 256, 0, stream>>>(Ow, owb, 1024 * 1024 / 4);

    // QKV projection: [4096,3072] = xb[4096,1024] * wqkv[3072,1024]^T
    gemm_bt<<<dim3(3072 / 64, 4096 / 64), 256, 0, stream>>>(xb, wqkv, qkv,
                                                            4096, 3072, 1024, 1024, 1024, 3072);
    // RoPE Q,K -> bf16 [bh][S][64]
    rope_kernel<<<4096, 512, 0, stream>>>(qkv, tp, qr, kr);
    // V -> Vt [bh][64][S]
    vtrans<<<dim3(NS / 64, NB * NH), 256, 0, stream>>>(qkv, vt);
    // attention
    attn_kernel<<<dim3(NS / 64, NB * NH), 256, 0, stream>>>(qr, kr, vt, ob);
    // output projection: out[4096,1024] = ob[4096,1024] * owb[1024,1024]^T
    gemm_bt<<<dim3(1024 / 64, 4096 / 64), 256, 0, stream>>>(ob, owb, out,
                                                            4096, 1024, 1024, 1024, 1024, 1024);
}

// Round 2
// 227.867 us; speedup vs baseline: 1.7287x; 1.7287x over previous
//
#include <hip/hip_runtime.h>

#define NB 2
#define NS 2048
#define NDM 1024
#define NH 16
#define NDK 64

typedef unsigned int u32;
typedef u32 u32x4 __attribute__((ext_vector_type(4)));
typedef float f32x4 __attribute__((ext_vector_type(4)));
typedef __bf16 bf16x8 __attribute__((ext_vector_type(8)));
typedef __bf16 bf16x4 __attribute__((ext_vector_type(4)));
typedef __bf16 bf16x2 __attribute__((ext_vector_type(2)));

__device__ __forceinline__ void gload_lds16(const __bf16* g, __bf16* l) {
    __builtin_amdgcn_global_load_lds(
        (const __attribute__((address_space(1))) unsigned int*)(g),
        (__attribute__((address_space(3))) unsigned int*)(l), 16, 0, 0);
}

// ---------------- fp32 -> bf16 cast (vectorized) ----------------
__global__ __launch_bounds__(256) void cvt_f32_bf16(const float* __restrict__ src,
                                                    __bf16* __restrict__ dst, int n4) {
    int i = blockIdx.x * blockDim.x + threadIdx.x;
    if (i >= n4) return;
    f32x4 v = *(const f32x4*)(src + (size_t)i * 4);
    bf16x4 o;
    o[0] = (__bf16)v[0]; o[1] = (__bf16)v[1]; o[2] = (__bf16)v[2]; o[3] = (__bf16)v[3];
    *(bf16x4*)(dst + (size_t)i * 4) = o;
}

// ---------------- GEMM (m97 structure): C[M,N] = A[M,K] * Bt[N,K]^T ----------------
// 128x128 tile, BK=64, 4 waves (2x2, each 64x64), global_load_lds width 16.
template <typename TOUT>
__global__ __launch_bounds__(256) void gemm_bt128(const __bf16* __restrict__ A,
                                                  const __bf16* __restrict__ Bt,
                                                  TOUT* __restrict__ C,
                                                  int K, int lda, int ldb, int ldc) {
    __shared__ __bf16 As[128 * 64];
    __shared__ __bf16 Bs[128 * 64];
    const int tid = threadIdx.x;
    const int lane = tid & 63, w = tid >> 6;
    const int wr = w >> 1, wc = w & 1;
    const int l15 = lane & 15, lg = lane >> 4;
    const int m0 = blockIdx.y * 128, n0 = blockIdx.x * 128;
    const int crow = lane >> 3;          // row within 8-row chunk
    const int ccol = (lane & 7) * 8;     // element col within 64

    f32x4 acc[4][4];
    const f32x4 z = {0.f, 0.f, 0.f, 0.f};
#pragma unroll
    for (int i = 0; i < 4; ++i)
#pragma unroll
        for (int jx = 0; jx < 4; ++jx) acc[i][jx] = z;

    for (int k0 = 0; k0 < K; k0 += 64) {
        __syncthreads();
#pragma unroll
        for (int ch = 0; ch < 4; ++ch) {
            const int cid = w * 4 + ch;
            const int ra = cid * 8 + crow;
            gload_lds16(&A[(size_t)(m0 + ra) * lda + k0 + ccol], &As[cid * 512]);
            gload_lds16(&Bt[(size_t)(n0 + ra) * ldb + k0 + ccol], &Bs[cid * 512]);
        }
        __syncthreads();
#pragma unroll
        for (int kc = 0; kc < 2; ++kc) {
            bf16x8 af[4], bfv[4];
#pragma unroll
            for (int i = 0; i < 4; ++i) {
                af[i]  = *(const bf16x8*)&As[(wr * 64 + i * 16 + l15) * 64 + kc * 32 + lg * 8];
                bfv[i] = *(const bf16x8*)&Bs[(wc * 64 + i * 16 + l15) * 64 + kc * 32 + lg * 8];
            }
#pragma unroll
            for (int sm = 0; sm < 4; ++sm)
#pragma unroll
                for (int sn = 0; sn < 4; ++sn)
                    acc[sm][sn] = __builtin_amdgcn_mfma_f32_16x16x32_bf16(af[sm], bfv[sn], acc[sm][sn], 0, 0, 0);
        }
    }
#pragma unroll
    for (int sm = 0; sm < 4; ++sm)
#pragma unroll
        for (int sn = 0; sn < 4; ++sn)
#pragma unroll
            for (int j = 0; j < 4; ++j) {
                const int row = m0 + wr * 64 + sm * 16 + lg * 4 + j;
                const int col = n0 + wc * 64 + sn * 16 + l15;
                C[(size_t)row * ldc + col] = (TOUT)acc[sm][sn][j];
            }
}

// ---------------- RoPE on Q and K halves (bf16 qkv in) ----------------
__global__ __launch_bounds__(512) void rope_kernel(const __bf16* __restrict__ qkv,
                                                   const int* __restrict__ tp,
                                                   __bf16* __restrict__ Qr,
                                                   __bf16* __restrict__ Kr) {
    const int row = blockIdx.x;           // b*S + s
    const int s = row & (NS - 1);
    const int b = row >> 11;
    const int t = threadIdx.x;            // 512 threads = 16 heads x 32 pairs
    const int h = t >> 5, jj = t & 31;
    const float pos = (float)tp[s];
    // 10000^(-j/32) = exp2(-j * log2(10000)/32)
    const float inv = exp2f(-0.41524101186092f * (float)jj);
    const float ang = pos * inv;
    float sn, cs;
    sincosf(ang, &sn, &cs);
    const __bf16* qp = qkv + (size_t)row * 3072 + h * 64 + 2 * jj;
    bf16x2 qv = *(const bf16x2*)qp;
    bf16x2 kv = *(const bf16x2*)(qp + 1024);
    const float q0 = (float)qv[0], q1 = (float)qv[1];
    const float k0 = (float)kv[0], k1 = (float)kv[1];
    const size_t o = ((size_t)(b * NH + h) * NS + s) * 64 + 2 * jj;
    bf16x2 qo, ko;
    qo[0] = (__bf16)(q0 * cs - q1 * sn); qo[1] = (__bf16)(q0 * sn + q1 * cs);
    ko[0] = (__bf16)(k0 * cs - k1 * sn); ko[1] = (__bf16)(k0 * sn + k1 * cs);
    *(bf16x2*)&Qr[o] = qo;
    *(bf16x2*)&Kr[o] = ko;
}

// ---------------- V transpose: qkv V-part (bf16) -> Vt [B*H, 64, S] ----------------
__global__ __launch_bounds__(256) void vtrans(const __bf16* __restrict__ qkv,
                                              __bf16* __restrict__ Vt) {
    const int bh = blockIdx.y;
    const int s0 = blockIdx.x * 64;
    const int b = bh >> 4, h = bh & 15;
    __shared__ __bf16 tile[64][72];
    const int t = threadIdx.x;
    const int sl = t >> 3, c8 = (t & 7) * 8;
#pragma unroll
    for (int p = 0; p < 2; ++p) {
        const int srow = sl + p * 32;
        bf16x8 v = *(const bf16x8*)&qkv[(size_t)(b * NS + s0 + srow) * 3072 + 2048 + h * 64 + c8];
        *(bf16x8*)&tile[srow][c8] = v;
    }
    __syncthreads();
    const int d = t >> 2;
#pragma unroll
    for (int p = 0; p < 2; ++p) {
        const int vec = (t & 3) + p * 4;
        bf16x8 o;
#pragma unroll
        for (int i = 0; i < 8; ++i) o[i] = tile[vec * 8 + i][d];
        *(bf16x8*)&Vt[((size_t)bh * 64 + d) * NS + s0 + vec * 8] = o;
    }
}

// ---------------- causal flash attention v2 ----------------
// grid (S/128, B*H), 256 threads = 4 waves; wave w owns rows {q0+16w..+15} and {q0+64+16w..+15}.
// K/V tiles (64 kv) double-buffered in LDS via global_load_lds, XOR-swizzled both sides.
__global__ __launch_bounds__(256) void attn2(const __bf16* __restrict__ Qr,
                                             const __bf16* __restrict__ Kr,
                                             const __bf16* __restrict__ Vt,
                                             __bf16* __restrict__ O) {
    const int bh = blockIdx.y;
    const int b = bh >> 4, h = bh & 15;
    const int q0 = blockIdx.x * 128;
    const int tid = threadIdx.x;
    const int w = tid >> 6, lane = tid & 63;
    const int l15 = lane & 15, lg = lane >> 4;
    const __bf16* Qb = Qr + (size_t)bh * NS * 64;
    const __bf16* Kb = Kr + (size_t)bh * NS * 64;
    const __bf16* Vb = Vt + (size_t)bh * 64 * NS;

    __shared__ __bf16 Ks[2][64 * 64];
    __shared__ __bf16 Vs[2][64 * 64];
    __shared__ __bf16 Pl[4][2][16 * 72];   // stride 72 el = 144B (16B aligned)

    const int rb0 = q0 + w * 16;
    const int rb1 = q0 + 64 + w * 16;
    const int rbv[2] = {rb0, rb1};

    // Q fragments, persistent
    bf16x8 qf[2][2];
#pragma unroll
    for (int rs = 0; rs < 2; ++rs)
#pragma unroll
        for (int kc = 0; kc < 2; ++kc)
            qf[rs][kc] = *(const bf16x8*)(Qb + (size_t)(rbv[rs] + l15) * 64 + kc * 32 + lg * 8);

    f32x4 oacc[2][4];
    const f32x4 z = {0.f, 0.f, 0.f, 0.f};
#pragma unroll
    for (int rs = 0; rs < 2; ++rs)
#pragma unroll
        for (int ct = 0; ct < 4; ++ct) oacc[rs][ct] = z;
    float m[2][4], lsum[2][4];
#pragma unroll
    for (int rs = 0; rs < 2; ++rs)
#pragma unroll
        for (int j = 0; j < 4; ++j) { m[rs][j] = -1e30f; lsum[rs][j] = 0.f; }

    const int crow = lane >> 3;                       // 0..7
    const int cswz = ((lane & 7) ^ crow) * 8;         // pre-swizzled source col (elements)

    // stage tile 0
#pragma unroll
    for (int p = 0; p < 2; ++p) {
        const int ch = w + p * 4;
        const int rt = ch * 8 + crow;
        gload_lds16(Kb + (size_t)rt * 64 + cswz, &Ks[0][ch * 512]);
        gload_lds16(Vb + (size_t)rt * NS + 0 + cswz, &Vs[0][ch * 512]);
    }
    __syncthreads();

    const int nt = (q0 >> 6) + 2;
    for (int t = 0; t < nt; ++t) {
        const int cur = t & 1;
        const int kv0 = t << 6;
        if (t + 1 < nt) {
            const int kv1 = kv0 + 64;
#pragma unroll
            for (int p = 0; p < 2; ++p) {
                const int ch = w + p * 4;
                const int rt = ch * 8 + crow;
                gload_lds16(Kb + (size_t)(kv1 + rt) * 64 + cswz, &Ks[cur ^ 1][ch * 512]);
                gload_lds16(Vb + (size_t)rt * NS + kv1 + cswz, &Vs[cur ^ 1][ch * 512]);
            }
        }
        // ---- QK^T (K frags shared across rowsets) ----
        f32x4 sc[2][4];
#pragma unroll
        for (int rs = 0; rs < 2; ++rs)
#pragma unroll
            for (int ct = 0; ct < 4; ++ct) sc[rs][ct] = z;
#pragma unroll
        for (int kc = 0; kc < 2; ++kc) {
            bf16x8 kf[4];
#pragma unroll
            for (int ct = 0; ct < 4; ++ct) {
                const int rt = ct * 16 + l15;
                kf[ct] = *(const bf16x8*)&Ks[cur][rt * 64 + ((kc * 32 + lg * 8) ^ ((rt & 7) << 3))];
            }
#pragma unroll
            for (int rs = 0; rs < 2; ++rs)
#pragma unroll
                for (int ct = 0; ct < 4; ++ct)
                    sc[rs][ct] = __builtin_amdgcn_mfma_f32_16x16x32_bf16(qf[rs][kc], kf[ct], sc[rs][ct], 0, 0, 0);
        }
        // ---- softmax + P write, per rowset ----
        bool act[2];
#pragma unroll
        for (int rs = 0; rs < 2; ++rs) {
            const int rbase = rbv[rs];
            act[rs] = (kv0 <= rbase + 15);
            if (!act[rs]) continue;
            const bool needmask = (kv0 + 63 > rbase);
            float alpha[4];
#pragma unroll
            for (int j = 0; j < 4; ++j) {
                const int rw = rbase + lg * 4 + j;
#pragma unroll
                for (int ct = 0; ct < 4; ++ct) {
                    float sv = sc[rs][ct][j] * 0.125f;
                    if (needmask && (kv0 + ct * 16 + l15 > rw)) sv = -1e30f;
                    sc[rs][ct][j] = sv;
                }
                float mt = fmaxf(fmaxf(sc[rs][0][j], sc[rs][1][j]), fmaxf(sc[rs][2][j], sc[rs][3][j]));
#pragma unroll
                for (int d = 1; d < 16; d <<= 1) mt = fmaxf(mt, __shfl_xor(mt, d, 64));
                const float mn = fmaxf(m[rs][j], mt);
                const float al = __expf(m[rs][j] - mn);
                m[rs][j] = mn;
                float ps = 0.f;
#pragma unroll
                for (int ct = 0; ct < 4; ++ct) {
                    const float p = __expf(sc[rs][ct][j] - mn);
                    sc[rs][ct][j] = p;
                    ps += p;
                }
#pragma unroll
                for (int d = 1; d < 16; d <<= 1) ps += __shfl_xor(ps, d, 64);
                lsum[rs][j] = lsum[rs][j] * al + ps;
                alpha[j] = al;
            }
#pragma unroll
            for (int ct = 0; ct < 4; ++ct)
#pragma unroll
                for (int j = 0; j < 4; ++j) oacc[rs][ct][j] *= alpha[j];
#pragma unroll
            for (int ct = 0; ct < 4; ++ct)
#pragma unroll
                for (int j = 0; j < 4; ++j)
                    Pl[w][rs][(lg * 4 + j) * 72 + ct * 16 + l15] = (__bf16)sc[rs][ct][j];
        }
        // same-wave LDS is in-order; just stop the compiler reordering P-writes vs PV ds_reads
        asm volatile("" ::: "memory");
        // ---- PV ----
#pragma unroll
        for (int kc = 0; kc < 2; ++kc) {
            bf16x8 vf[4];
#pragma unroll
            for (int ct = 0; ct < 4; ++ct) {
                const int rt = ct * 16 + l15;
                vf[ct] = *(const bf16x8*)&Vs[cur][rt * 64 + ((kc * 32 + lg * 8) ^ ((rt & 7) << 3))];
            }
#pragma unroll
            for (int rs = 0; rs < 2; ++rs) {
                if (!act[rs]) continue;
                bf16x8 pf = *(const bf16x8*)&Pl[w][rs][l15 * 72 + kc * 32 + lg * 8];
#pragma unroll
                for (int ct = 0; ct < 4; ++ct)
                    oacc[rs][ct] = __builtin_amdgcn_mfma_f32_16x16x32_bf16(pf, vf[ct], oacc[rs][ct], 0, 0, 0);
            }
        }
        __syncthreads();   // vmcnt(0)+lgkm drain: next buffer ready, all waves done with cur
    }
    // ---- epilogue ----
#pragma unroll
    for (int rs = 0; rs < 2; ++rs)
#pragma unroll
        for (int ct = 0; ct < 4; ++ct)
#pragma unroll
            for (int j = 0; j < 4; ++j) {
                const int rw = rbv[rs] + lg * 4 + j;
                const float val = oacc[rs][ct][j] / lsum[rs][j];
                O[(size_t)(b * NS + rw) * NDM + h * 64 + ct * 16 + l15] = (__bf16)val;
            }
}

// ---------------- launch ----------------
extern "C" void kernel_launch(void* const* d_in, const int* in_sizes, int n_in,
                              void* d_out, int out_size, void* d_ws, size_t ws_size,
                              hipStream_t stream) {
    const float* x  = (const float*)d_in[0];
    const float* Qw = (const float*)d_in[1];
    const float* Kw = (const float*)d_in[2];
    const float* Vw = (const float*)d_in[3];
    const float* Ow = (const float*)d_in[4];
    const int*   tp = (const int*)d_in[5];
    float* out = (float*)d_out;

    char* ws = (char*)d_ws;
    size_t off = 0;
    auto alloc = [&](size_t bytes) -> void* {
        void* p = ws + off;
        off += (bytes + 255) & ~(size_t)255;
        return p;
    };
    __bf16* xb   = (__bf16*)alloc((size_t)4096 * 1024 * 2);
    __bf16* wqkv = (__bf16*)alloc((size_t)3072 * 1024 * 2);
    __bf16* owb  = (__bf16*)alloc((size_t)1024 * 1024 * 2);
    __bf16* qkv  = (__bf16*)alloc((size_t)4096 * 3072 * 2);
    __bf16* qr   = (__bf16*)alloc((size_t)32 * 2048 * 64 * 2);
    __bf16* kr   = (__bf16*)alloc((size_t)32 * 2048 * 64 * 2);
    __bf16* vt   = (__bf16*)alloc((size_t)32 * 64 * 2048 * 2);
    __bf16* ob   = (__bf16*)alloc((size_t)4096 * 1024 * 2);

    // casts
    cvt_f32_bf16<<<4096, 256, 0, stream>>>(x, xb, 4096 * 1024 / 4);
    cvt_f32_bf16<<<1024, 256, 0, stream>>>(Qw, wqkv, 1024 * 1024 / 4);
    cvt_f32_bf16<<<1024, 256, 0, stream>>>(Kw, wqkv + 1024 * 1024, 1024 * 1024 / 4);
    cvt_f32_bf16<<<1024, 256, 0, stream>>>(Vw, wqkv + 2048 * 1024, 1024 * 1024 / 4);
    cvt_f32_bf16<<<1024, 256, 0, stream>>>(Ow, owb, 1024 * 1024 / 4);

    // QKV projection: qkv[4096,3072] = xb * wqkv^T  (bf16 out)
    gemm_bt128<__bf16><<<dim3(3072 / 128, 4096 / 128), 256, 0, stream>>>(
        xb, wqkv, qkv, 1024, 1024, 1024, 3072);
    // RoPE Q,K -> [bh][S][64]
    rope_kernel<<<4096, 512, 0, stream>>>(qkv, tp, qr, kr);
    // V -> Vt [bh][64][S]
    vtrans<<<dim3(NS / 64, NB * NH), 256, 0, stream>>>(qkv, vt);
    // attention
    attn2<<<dim3(NS / 128, NB * NH), 256, 0, stream>>>(qr, kr, vt, ob);
    // output projection: out[4096,1024] = ob * owb^T (fp32 out)
    gemm_bt128<float><<<dim3(1024 / 128, 4096 / 128), 256, 0, stream>>>(
        ob, owb, out, 1024, 1024, 1024, 1024);
}

// Round 3
// 188.313 us; speedup vs baseline: 2.0918x; 1.2100x over previous
//
#include <hip/hip_runtime.h>

#define NB 2
#define NS 2048
#define NDM 1024
#define NH 16
#define NDK 64

typedef unsigned int u32;
typedef u32 u32x4 __attribute__((ext_vector_type(4)));
typedef float f32x4 __attribute__((ext_vector_type(4)));
typedef __bf16 bf16x8 __attribute__((ext_vector_type(8)));
typedef __bf16 bf16x4 __attribute__((ext_vector_type(4)));
typedef __bf16 bf16x2 __attribute__((ext_vector_type(2)));

__device__ __forceinline__ void gload_lds16(const __bf16* g, __bf16* l) {
    __builtin_amdgcn_global_load_lds(
        (const __attribute__((address_space(1))) unsigned int*)(g),
        (__attribute__((address_space(3))) unsigned int*)(l), 16, 0, 0);
}

// ---------------- fp32 -> bf16 cast (vectorized) ----------------
__global__ __launch_bounds__(256) void cvt_f32_bf16(const float* __restrict__ src,
                                                    __bf16* __restrict__ dst, int n4) {
    int i = blockIdx.x * blockDim.x + threadIdx.x;
    if (i >= n4) return;
    f32x4 v = *(const f32x4*)(src + (size_t)i * 4);
    bf16x4 o;
    o[0] = (__bf16)v[0]; o[1] = (__bf16)v[1]; o[2] = (__bf16)v[2]; o[3] = (__bf16)v[3];
    *(bf16x4*)(dst + (size_t)i * 4) = o;
}

// ---------------- GEMM (m97 structure): C[M,N] = A[M,K] * Bt[N,K]^T ----------------
template <typename TOUT>
__global__ __launch_bounds__(256) void gemm_bt128(const __bf16* __restrict__ A,
                                                  const __bf16* __restrict__ Bt,
                                                  TOUT* __restrict__ C,
                                                  int K, int lda, int ldb, int ldc) {
    __shared__ __bf16 As[128 * 64];
    __shared__ __bf16 Bs[128 * 64];
    const int tid = threadIdx.x;
    const int lane = tid & 63, w = tid >> 6;
    const int wr = w >> 1, wc = w & 1;
    const int l15 = lane & 15, lg = lane >> 4;
    const int m0 = blockIdx.y * 128, n0 = blockIdx.x * 128;
    const int crow = lane >> 3;
    const int ccol = (lane & 7) * 8;

    f32x4 acc[4][4];
    const f32x4 z = {0.f, 0.f, 0.f, 0.f};
#pragma unroll
    for (int i = 0; i < 4; ++i)
#pragma unroll
        for (int jx = 0; jx < 4; ++jx) acc[i][jx] = z;

    for (int k0 = 0; k0 < K; k0 += 64) {
        __syncthreads();
#pragma unroll
        for (int ch = 0; ch < 4; ++ch) {
            const int cid = w * 4 + ch;
            const int ra = cid * 8 + crow;
            gload_lds16(&A[(size_t)(m0 + ra) * lda + k0 + ccol], &As[cid * 512]);
            gload_lds16(&Bt[(size_t)(n0 + ra) * ldb + k0 + ccol], &Bs[cid * 512]);
        }
        __syncthreads();
#pragma unroll
        for (int kc = 0; kc < 2; ++kc) {
            bf16x8 af[4], bfv[4];
#pragma unroll
            for (int i = 0; i < 4; ++i) {
                af[i]  = *(const bf16x8*)&As[(wr * 64 + i * 16 + l15) * 64 + kc * 32 + lg * 8];
                bfv[i] = *(const bf16x8*)&Bs[(wc * 64 + i * 16 + l15) * 64 + kc * 32 + lg * 8];
            }
#pragma unroll
            for (int sm = 0; sm < 4; ++sm)
#pragma unroll
                for (int sn = 0; sn < 4; ++sn)
                    acc[sm][sn] = __builtin_amdgcn_mfma_f32_16x16x32_bf16(af[sm], bfv[sn], acc[sm][sn], 0, 0, 0);
        }
    }
#pragma unroll
    for (int sm = 0; sm < 4; ++sm)
#pragma unroll
        for (int sn = 0; sn < 4; ++sn)
#pragma unroll
            for (int j = 0; j < 4; ++j) {
                const int row = m0 + wr * 64 + sm * 16 + lg * 4 + j;
                const int col = n0 + wc * 64 + sn * 16 + l15;
                C[(size_t)row * ldc + col] = (TOUT)acc[sm][sn][j];
            }
}

// ---------------- RoPE on Q and K halves (bf16 qkv in). Q pre-scaled by 1/8. ----------------
__global__ __launch_bounds__(512) void rope_kernel(const __bf16* __restrict__ qkv,
                                                   const int* __restrict__ tp,
                                                   __bf16* __restrict__ Qr,
                                                   __bf16* __restrict__ Kr) {
    const int row = blockIdx.x;           // b*S + s
    const int s = row & (NS - 1);
    const int b = row >> 11;
    const int t = threadIdx.x;            // 16 heads x 32 pairs
    const int h = t >> 5, jj = t & 31;
    const float pos = (float)tp[s];
    const float inv = exp2f(-0.41524101186092f * (float)jj);  // 10000^(-j/32)
    const float ang = pos * inv;
    float sn, cs;
    sincosf(ang, &sn, &cs);
    const __bf16* qp = qkv + (size_t)row * 3072 + h * 64 + 2 * jj;
    bf16x2 qv = *(const bf16x2*)qp;
    bf16x2 kv = *(const bf16x2*)(qp + 1024);
    const float q0 = (float)qv[0], q1 = (float)qv[1];
    const float k0 = (float)kv[0], k1 = (float)kv[1];
    const size_t o = ((size_t)(b * NH + h) * NS + s) * 64 + 2 * jj;
    bf16x2 qo, ko;
    qo[0] = (__bf16)((q0 * cs - q1 * sn) * 0.125f);  // fold 1/sqrt(DK) into Q (exact pow2)
    qo[1] = (__bf16)((q0 * sn + q1 * cs) * 0.125f);
    ko[0] = (__bf16)(k0 * cs - k1 * sn); ko[1] = (__bf16)(k0 * sn + k1 * cs);
    *(bf16x2*)&Qr[o] = qo;
    *(bf16x2*)&Kr[o] = ko;
}

// ---------------- V transpose: qkv V-part (bf16) -> Vt [B*H, 64, S] ----------------
__global__ __launch_bounds__(256) void vtrans(const __bf16* __restrict__ qkv,
                                              __bf16* __restrict__ Vt) {
    const int bh = blockIdx.y;
    const int s0 = blockIdx.x * 64;
    const int b = bh >> 4, h = bh & 15;
    __shared__ __bf16 tile[64][72];
    const int t = threadIdx.x;
    const int sl = t >> 3, c8 = (t & 7) * 8;
#pragma unroll
    for (int pp = 0; pp < 2; ++pp) {
        const int srow = sl + pp * 32;
        bf16x8 v = *(const bf16x8*)&qkv[(size_t)(b * NS + s0 + srow) * 3072 + 2048 + h * 64 + c8];
        *(bf16x8*)&tile[srow][c8] = v;
    }
    __syncthreads();
    const int d = t >> 2;
#pragma unroll
    for (int pp = 0; pp < 2; ++pp) {
        const int vec = (t & 3) + pp * 4;
        bf16x8 o;
#pragma unroll
        for (int i = 0; i < 8; ++i) o[i] = tile[vec * 8 + i][d];
        *(bf16x8*)&Vt[((size_t)bh * 64 + d) * NS + s0 + vec * 8] = o;
    }
}

// ---------------- causal flash attention v3: causal-paired, XCD-mapped ----------------
// 512 blocks (1-D). lid -> (xcd = lid&7 owns 4 heads; p = q-tile pair index).
// Block processes 64-row q-tiles {p, 31-p} simultaneously as the two per-wave rowsets,
// sharing one KV stream over tiles 0..31-p. Constant 33 MFMA-units of work per block.
__global__ __launch_bounds__(256) void attn3(const __bf16* __restrict__ Qr,
                                             const __bf16* __restrict__ Kr,
                                             const __bf16* __restrict__ Vt,
                                             __bf16* __restrict__ O) {
    const int lid = blockIdx.x;
    const int xcd = lid & 7, ix = lid >> 3;
    const int bh = xcd * 4 + (ix & 3);     // 4 heads per XCD -> K/V working set 2MB < 4MB L2
    const int p  = ix >> 2;                // 0..15
    const int b = bh >> 4, h = bh & 15;
    const int tid = threadIdx.x;
    const int w = tid >> 6, lane = tid & 63;
    const int l15 = lane & 15, lg = lane >> 4;
    const __bf16* Qb = Qr + (size_t)bh * NS * 64;
    const __bf16* Kb = Kr + (size_t)bh * NS * 64;
    const __bf16* Vb = Vt + (size_t)bh * 64 * NS;

    __shared__ __bf16 Ks[2][64 * 64];
    __shared__ __bf16 Vs[2][64 * 64];
    __shared__ __bf16 Pl[4][2][16 * 72];

    const int rbv[2] = {p * 64 + w * 16, (31 - p) * 64 + w * 16};

    bf16x8 qf[2][2];
#pragma unroll
    for (int rs = 0; rs < 2; ++rs)
#pragma unroll
        for (int kc = 0; kc < 2; ++kc)
            qf[rs][kc] = *(const bf16x8*)(Qb + (size_t)(rbv[rs] + l15) * 64 + kc * 32 + lg * 8);

    f32x4 oacc[2][4];
    const f32x4 z = {0.f, 0.f, 0.f, 0.f};
#pragma unroll
    for (int rs = 0; rs < 2; ++rs)
#pragma unroll
        for (int ct = 0; ct < 4; ++ct) oacc[rs][ct] = z;
    float m[2][4], lsum[2][4];
#pragma unroll
    for (int rs = 0; rs < 2; ++rs)
#pragma unroll
        for (int j = 0; j < 4; ++j) { m[rs][j] = -1e30f; lsum[rs][j] = 0.f; }

    const int crow = lane >> 3;
    const int cswz = ((lane & 7) ^ crow) * 8;   // pre-swizzled source col

    // stage tile 0
#pragma unroll
    for (int pp = 0; pp < 2; ++pp) {
        const int ch = w + pp * 4;
        const int rt = ch * 8 + crow;
        gload_lds16(Kb + (size_t)rt * 64 + cswz, &Ks[0][ch * 512]);
        gload_lds16(Vb + (size_t)rt * NS + 0 + cswz, &Vs[0][ch * 512]);
    }
    __syncthreads();

    const int nt = 32 - p;
    for (int t = 0; t < nt; ++t) {
        const int cur = t & 1;
        const int kv0 = t << 6;
        if (t + 1 < nt) {
            const int kv1 = kv0 + 64;
#pragma unroll
            for (int pp = 0; pp < 2; ++pp) {
                const int ch = w + pp * 4;
                const int rt = ch * 8 + crow;
                gload_lds16(Kb + (size_t)(kv1 + rt) * 64 + cswz, &Ks[cur ^ 1][ch * 512]);
                gload_lds16(Vb + (size_t)rt * NS + kv1 + cswz, &Vs[cur ^ 1][ch * 512]);
            }
        }
        bool act[2];
        act[0] = (kv0 <= rbv[0] + 15);
        act[1] = true;
        // ---- QK^T (K frags shared across rowsets; inactive rowset skipped) ----
        f32x4 sc[2][4];
#pragma unroll
        for (int rs = 0; rs < 2; ++rs)
            if (act[rs])
#pragma unroll
                for (int ct = 0; ct < 4; ++ct) sc[rs][ct] = z;
#pragma unroll
        for (int kc = 0; kc < 2; ++kc) {
            bf16x8 kf[4];
#pragma unroll
            for (int ct = 0; ct < 4; ++ct) {
                const int rt = ct * 16 + l15;
                kf[ct] = *(const bf16x8*)&Ks[cur][rt * 64 + ((kc * 32 + lg * 8) ^ ((rt & 7) << 3))];
            }
#pragma unroll
            for (int rs = 0; rs < 2; ++rs)
                if (act[rs])
#pragma unroll
                    for (int ct = 0; ct < 4; ++ct)
                        sc[rs][ct] = __builtin_amdgcn_mfma_f32_16x16x32_bf16(qf[rs][kc], kf[ct], sc[rs][ct], 0, 0, 0);
        }
        // ---- softmax + P write, per rowset ----
#pragma unroll
        for (int rs = 0; rs < 2; ++rs) {
            if (!act[rs]) continue;
            const int rbase = rbv[rs];
            const bool needmask = (kv0 + 63 > rbase);
            float alpha[4];
            bool resc = false;
#pragma unroll
            for (int j = 0; j < 4; ++j) {
                const int rw = rbase + lg * 4 + j;
                if (needmask) {
#pragma unroll
                    for (int ct = 0; ct < 4; ++ct)
                        if (kv0 + ct * 16 + l15 > rw) sc[rs][ct][j] = -1e30f;
                }
                float mt = fmaxf(fmaxf(sc[rs][0][j], sc[rs][1][j]), fmaxf(sc[rs][2][j], sc[rs][3][j]));
#pragma unroll
                for (int d = 1; d < 16; d <<= 1) mt = fmaxf(mt, __shfl_xor(mt, d, 64));
                if (__all(mt - m[rs][j] <= 8.0f)) {
                    alpha[j] = 1.0f;               // defer-max: keep old m, P bounded by e^8
                } else {
                    const float mn = fmaxf(m[rs][j], mt);
                    alpha[j] = __expf(m[rs][j] - mn);
                    m[rs][j] = mn;
                    resc = true;
                }
                float ps = 0.f;
#pragma unroll
                for (int ct = 0; ct < 4; ++ct) {
                    const float pv = __expf(sc[rs][ct][j] - m[rs][j]);
                    sc[rs][ct][j] = pv;
                    ps += pv;
                }
#pragma unroll
                for (int d = 1; d < 16; d <<= 1) ps += __shfl_xor(ps, d, 64);
                lsum[rs][j] = lsum[rs][j] * alpha[j] + ps;
            }
            if (resc) {
#pragma unroll
                for (int ct = 0; ct < 4; ++ct)
#pragma unroll
                    for (int j = 0; j < 4; ++j) oacc[rs][ct][j] *= alpha[j];
            }
#pragma unroll
            for (int ct = 0; ct < 4; ++ct)
#pragma unroll
                for (int j = 0; j < 4; ++j)
                    Pl[w][rs][(lg * 4 + j) * 72 + ct * 16 + l15] = (__bf16)sc[rs][ct][j];
        }
        asm volatile("" ::: "memory");
        // ---- PV ----
#pragma unroll
        for (int kc = 0; kc < 2; ++kc) {
            bf16x8 vf[4];
#pragma unroll
            for (int ct = 0; ct < 4; ++ct) {
                const int rt = ct * 16 + l15;
                vf[ct] = *(const bf16x8*)&Vs[cur][rt * 64 + ((kc * 32 + lg * 8) ^ ((rt & 7) << 3))];
            }
#pragma unroll
            for (int rs = 0; rs < 2; ++rs) {
                if (!act[rs]) continue;
                bf16x8 pf = *(const bf16x8*)&Pl[w][rs][l15 * 72 + kc * 32 + lg * 8];
#pragma unroll
                for (int ct = 0; ct < 4; ++ct)
                    oacc[rs][ct] = __builtin_amdgcn_mfma_f32_16x16x32_bf16(pf, vf[ct], oacc[rs][ct], 0, 0, 0);
            }
        }
        __syncthreads();
    }
    // ---- epilogue ----
#pragma unroll
    for (int rs = 0; rs < 2; ++rs)
#pragma unroll
        for (int ct = 0; ct < 4; ++ct)
#pragma unroll
            for (int j = 0; j < 4; ++j) {
                const int rw = rbv[rs] + lg * 4 + j;
                const float val = oacc[rs][ct][j] / lsum[rs][j];
                O[(size_t)(b * NS + rw) * NDM + h * 64 + ct * 16 + l15] = (__bf16)val;
            }
}

// ---------------- launch ----------------
extern "C" void kernel_launch(void* const* d_in, const int* in_sizes, int n_in,
                              void* d_out, int out_size, void* d_ws, size_t ws_size,
                              hipStream_t stream) {
    const float* x  = (const float*)d_in[0];
    const float* Qw = (const float*)d_in[1];
    const float* Kw = (const float*)d_in[2];
    const float* Vw = (const float*)d_in[3];
    const float* Ow = (const float*)d_in[4];
    const int*   tp = (const int*)d_in[5];
    float* out = (float*)d_out;

    char* ws = (char*)d_ws;
    size_t off = 0;
    auto alloc = [&](size_t bytes) -> void* {
        void* p = ws + off;
        off += (bytes + 255) & ~(size_t)255;
        return p;
    };
    __bf16* xb   = (__bf16*)alloc((size_t)4096 * 1024 * 2);
    __bf16* wqkv = (__bf16*)alloc((size_t)3072 * 1024 * 2);
    __bf16* owb  = (__bf16*)alloc((size_t)1024 * 1024 * 2);
    __bf16* qkv  = (__bf16*)alloc((size_t)4096 * 3072 * 2);
    __bf16* qr   = (__bf16*)alloc((size_t)32 * 2048 * 64 * 2);
    __bf16* kr   = (__bf16*)alloc((size_t)32 * 2048 * 64 * 2);
    __bf16* vt   = (__bf16*)alloc((size_t)32 * 64 * 2048 * 2);
    __bf16* ob   = (__bf16*)alloc((size_t)4096 * 1024 * 2);

    cvt_f32_bf16<<<4096, 256, 0, stream>>>(x, xb, 4096 * 1024 / 4);
    cvt_f32_bf16<<<1024, 256, 0, stream>>>(Qw, wqkv, 1024 * 1024 / 4);
    cvt_f32_bf16<<<1024, 256, 0, stream>>>(Kw, wqkv + 1024 * 1024, 1024 * 1024 / 4);
    cvt_f32_bf16<<<1024, 256, 0, stream>>>(Vw, wqkv + 2048 * 1024, 1024 * 1024 / 4);
    cvt_f32_bf16<<<1024, 256, 0, stream>>>(Ow, owb, 1024 * 1024 / 4);

    gemm_bt128<__bf16><<<dim3(3072 / 128, 4096 / 128), 256, 0, stream>>>(
        xb, wqkv, qkv, 1024, 1024, 1024, 3072);
    rope_kernel<<<4096, 512, 0, stream>>>(qkv, tp, qr, kr);
    vtrans<<<dim3(NS / 64, NB * NH), 256, 0, stream>>>(qkv, vt);
    attn3<<<dim3(512), 256, 0, stream>>>(qr, kr, vt, ob);
    gemm_bt128<float><<<dim3(1024 / 128, 4096 / 128), 256, 0, stream>>>(
        ob, owb, out, 1024, 1024, 1024, 1024);
}

// Round 4
// 144.617 us; speedup vs baseline: 2.7238x; 1.3022x over previous
//
#include <hip/hip_runtime.h>

#define NB 2
#define NS 2048
#define NDM 1024
#define NH 16
#define NDK 64

typedef unsigned int u32;
typedef u32 u32x4 __attribute__((ext_vector_type(4)));
typedef float f32x4 __attribute__((ext_vector_type(4)));
typedef __bf16 bf16x8 __attribute__((ext_vector_type(8)));
typedef __bf16 bf16x4 __attribute__((ext_vector_type(4)));
typedef __bf16 bf16x2 __attribute__((ext_vector_type(2)));

__device__ __forceinline__ void gload_lds16(const __bf16* g, __bf16* l) {
    __builtin_amdgcn_global_load_lds(
        (const __attribute__((address_space(1))) unsigned int*)(g),
        (__attribute__((address_space(3))) unsigned int*)(l), 16, 0, 0);
}

// ---------------- fp32 -> bf16 cast (x input) ----------------
__global__ __launch_bounds__(256) void cvt_f32_bf16(const float* __restrict__ src,
                                                    __bf16* __restrict__ dst, int n4) {
    int i = blockIdx.x * blockDim.x + threadIdx.x;
    if (i >= n4) return;
    f32x4 v = *(const f32x4*)(src + (size_t)i * 4);
    bf16x4 o;
    o[0] = (__bf16)v[0]; o[1] = (__bf16)v[1]; o[2] = (__bf16)v[2]; o[3] = (__bf16)v[3];
    *(bf16x4*)(dst + (size_t)i * 4) = o;
}

// ---------------- all 4 weight casts in one launch ----------------
__global__ __launch_bounds__(256) void cvt_weights(const float* __restrict__ q,
                                                   const float* __restrict__ k,
                                                   const float* __restrict__ v,
                                                   const float* __restrict__ o,
                                                   __bf16* __restrict__ wqkv,
                                                   __bf16* __restrict__ owb) {
    const int seg = blockIdx.y;
    const float* src = (seg == 0) ? q : (seg == 1) ? k : (seg == 2) ? v : o;
    __bf16* dst = (seg == 3) ? owb : wqkv + (size_t)seg * 1024 * 1024;
    const int i = blockIdx.x * 256 + threadIdx.x;
    f32x4 vv = *(const f32x4*)(src + (size_t)i * 4);
    bf16x4 ov;
    ov[0] = (__bf16)vv[0]; ov[1] = (__bf16)vv[1]; ov[2] = (__bf16)vv[2]; ov[3] = (__bf16)vv[3];
    *(bf16x4*)(dst + (size_t)i * 4) = ov;
}

// ---------------- GEMM (m97 structure): C[M,N] = A[M,K] * Bt[N,K]^T ----------------
template <typename TOUT>
__global__ __launch_bounds__(256) void gemm_bt128(const __bf16* __restrict__ A,
                                                  const __bf16* __restrict__ Bt,
                                                  TOUT* __restrict__ C,
                                                  int K, int lda, int ldb, int ldc) {
    __shared__ __bf16 As[128 * 64];
    __shared__ __bf16 Bs[128 * 64];
    const int tid = threadIdx.x;
    const int lane = tid & 63, w = tid >> 6;
    const int wr = w >> 1, wc = w & 1;
    const int l15 = lane & 15, lg = lane >> 4;
    const int m0 = blockIdx.y * 128, n0 = blockIdx.x * 128;
    const int crow = lane >> 3;
    const int ccol = (lane & 7) * 8;

    f32x4 acc[4][4];
    const f32x4 z = {0.f, 0.f, 0.f, 0.f};
#pragma unroll
    for (int i = 0; i < 4; ++i)
#pragma unroll
        for (int jx = 0; jx < 4; ++jx) acc[i][jx] = z;

    for (int k0 = 0; k0 < K; k0 += 64) {
        __syncthreads();
#pragma unroll
        for (int ch = 0; ch < 4; ++ch) {
            const int cid = w * 4 + ch;
            const int ra = cid * 8 + crow;
            gload_lds16(&A[(size_t)(m0 + ra) * lda + k0 + ccol], &As[cid * 512]);
            gload_lds16(&Bt[(size_t)(n0 + ra) * ldb + k0 + ccol], &Bs[cid * 512]);
        }
        __syncthreads();
#pragma unroll
        for (int kc = 0; kc < 2; ++kc) {
            bf16x8 af[4], bfv[4];
#pragma unroll
            for (int i = 0; i < 4; ++i) {
                af[i]  = *(const bf16x8*)&As[(wr * 64 + i * 16 + l15) * 64 + kc * 32 + lg * 8];
                bfv[i] = *(const bf16x8*)&Bs[(wc * 64 + i * 16 + l15) * 64 + kc * 32 + lg * 8];
            }
#pragma unroll
            for (int sm = 0; sm < 4; ++sm)
#pragma unroll
                for (int sn = 0; sn < 4; ++sn)
                    acc[sm][sn] = __builtin_amdgcn_mfma_f32_16x16x32_bf16(af[sm], bfv[sn], acc[sm][sn], 0, 0, 0);
        }
    }
#pragma unroll
    for (int sm = 0; sm < 4; ++sm)
#pragma unroll
        for (int sn = 0; sn < 4; ++sn)
#pragma unroll
            for (int j = 0; j < 4; ++j) {
                const int row = m0 + wr * 64 + sm * 16 + lg * 4 + j;
                const int col = n0 + wc * 64 + sn * 16 + l15;
                C[(size_t)row * ldc + col] = (TOUT)acc[sm][sn][j];
            }
}

// ---------------- RoPE on Q and K halves (bf16 qkv in). Q pre-scaled by 1/8. ----------------
__global__ __launch_bounds__(512) void rope_kernel(const __bf16* __restrict__ qkv,
                                                   const int* __restrict__ tp,
                                                   __bf16* __restrict__ Qr,
                                                   __bf16* __restrict__ Kr) {
    const int row = blockIdx.x;           // b*S + s
    const int s = row & (NS - 1);
    const int b = row >> 11;
    const int t = threadIdx.x;            // 16 heads x 32 pairs
    const int h = t >> 5, jj = t & 31;
    const float pos = (float)tp[s];
    const float inv = exp2f(-0.41524101186092f * (float)jj);  // 10000^(-j/32)
    const float ang = pos * inv;
    float sn, cs;
    sincosf(ang, &sn, &cs);
    const __bf16* qp = qkv + (size_t)row * 3072 + h * 64 + 2 * jj;
    bf16x2 qv = *(const bf16x2*)qp;
    bf16x2 kv = *(const bf16x2*)(qp + 1024);
    const float q0 = (float)qv[0], q1 = (float)qv[1];
    const float k0 = (float)kv[0], k1 = (float)kv[1];
    const size_t o = ((size_t)(b * NH + h) * NS + s) * 64 + 2 * jj;
    bf16x2 qo, ko;
    qo[0] = (__bf16)((q0 * cs - q1 * sn) * 0.125f);
    qo[1] = (__bf16)((q0 * sn + q1 * cs) * 0.125f);
    ko[0] = (__bf16)(k0 * cs - k1 * sn); ko[1] = (__bf16)(k0 * sn + k1 * cs);
    *(bf16x2*)&Qr[o] = qo;
    *(bf16x2*)&Kr[o] = ko;
}

// ---------------- V transpose: qkv V-part (bf16) -> Vt [B*H, 64, S] ----------------
__global__ __launch_bounds__(256) void vtrans(const __bf16* __restrict__ qkv,
                                              __bf16* __restrict__ Vt) {
    const int bh = blockIdx.y;
    const int s0 = blockIdx.x * 64;
    const int b = bh >> 4, h = bh & 15;
    __shared__ __bf16 tile[64][72];
    const int t = threadIdx.x;
    const int sl = t >> 3, c8 = (t & 7) * 8;
#pragma unroll
    for (int pp = 0; pp < 2; ++pp) {
        const int srow = sl + pp * 32;
        bf16x8 v = *(const bf16x8*)&qkv[(size_t)(b * NS + s0 + srow) * 3072 + 2048 + h * 64 + c8];
        *(bf16x8*)&tile[srow][c8] = v;
    }
    __syncthreads();
    const int d = t >> 2;
#pragma unroll
    for (int pp = 0; pp < 2; ++pp) {
        const int vec = (t & 3) + pp * 4;
        bf16x8 o;
#pragma unroll
        for (int i = 0; i < 8; ++i) o[i] = tile[vec * 8 + i][d];
        *(bf16x8*)&Vt[((size_t)bh * 64 + d) * NS + s0 + vec * 8] = o;
    }
}

// K staging permutation: LDS slot rt holds K row kperm(rt) of the tile, so that
// after swapped QK^T (mfma(K,Q) -> S^T) each lane's registers hold exactly the
// contiguous-kv runs the PV B-fragment needs (zero cross-lane P exchange).
__device__ __forceinline__ int kperm(int rt) {
    const int ct = rt >> 4, rr = rt & 15;
    return ((rr >> 2) << 3) + ((ct >> 1) << 5) + ((ct & 1) << 2) + (rr & 3);
}

// ---------------- causal flash attention v4: swapped QK^T, in-lane softmax ----------------
// 512 blocks. Block handles q-tiles {p, 31-p} as two rowsets sharing one KV stream.
// Lane (l15,lg): q-row = rbase + l15; regs sc[ct][j] = S^T at kv = 32*(ct>>1)+lg*8+4*(ct&1)+j.
__global__ __launch_bounds__(256) void attn4(const __bf16* __restrict__ Qr,
                                             const __bf16* __restrict__ Kr,
                                             const __bf16* __restrict__ Vt,
                                             __bf16* __restrict__ O) {
    const int lid = blockIdx.x;
    const int xcd = lid & 7, ix = lid >> 3;
    const int bh = xcd * 4 + (ix & 3);     // 4 heads per XCD -> K/V set 2MB < 4MB L2
    const int p  = ix >> 2;                // 0..15
    const int b = bh >> 4, h = bh & 15;
    const int tid = threadIdx.x;
    const int w = tid >> 6, lane = tid & 63;
    const int l15 = lane & 15, lg = lane >> 4;
    const __bf16* Qb = Qr + (size_t)bh * NS * 64;
    const __bf16* Kb = Kr + (size_t)bh * NS * 64;
    const __bf16* Vb = Vt + (size_t)bh * 64 * NS;

    __shared__ __bf16 Ks[2][64 * 64];
    __shared__ __bf16 Vs[2][64 * 64];

    const int rbv[2] = {p * 64 + w * 16, (31 - p) * 64 + w * 16};

    // Q B-fragments (col = l15 = q-row), persistent
    bf16x8 qf[2][2];
#pragma unroll
    for (int rs = 0; rs < 2; ++rs)
#pragma unroll
        for (int kc = 0; kc < 2; ++kc)
            qf[rs][kc] = *(const bf16x8*)(Qb + (size_t)(rbv[rs] + l15) * 64 + kc * 32 + lg * 8);

    // O^T accumulators: oacc[rs][ct][j] = O^T[d=ct*16+lg*4+j][q=l15]
    f32x4 oacc[2][4];
    const f32x4 z = {0.f, 0.f, 0.f, 0.f};
#pragma unroll
    for (int rs = 0; rs < 2; ++rs)
#pragma unroll
        for (int ct = 0; ct < 4; ++ct) oacc[rs][ct] = z;
    float m[2], lsum[2];
#pragma unroll
    for (int rs = 0; rs < 2; ++rs) { m[rs] = -1e30f; lsum[rs] = 0.f; }

    const int crow = lane >> 3;
    const int cswz = ((lane & 7) ^ crow) * 8;   // pre-swizzled source col

    // stage tile 0 (K rows permuted)
#pragma unroll
    for (int pp = 0; pp < 2; ++pp) {
        const int ch = w + pp * 4;
        const int rt = ch * 8 + crow;
        gload_lds16(Kb + (size_t)kperm(rt) * 64 + cswz, &Ks[0][ch * 512]);
        gload_lds16(Vb + (size_t)rt * NS + 0 + cswz, &Vs[0][ch * 512]);
    }
    __syncthreads();

    const int nt = 32 - p;
    for (int t = 0; t < nt; ++t) {
        const int cur = t & 1;
        const int kv0 = t << 6;
        if (t + 1 < nt) {
            const int kv1 = kv0 + 64;
#pragma unroll
            for (int pp = 0; pp < 2; ++pp) {
                const int ch = w + pp * 4;
                const int rt = ch * 8 + crow;
                gload_lds16(Kb + (size_t)(kv1 + kperm(rt)) * 64 + cswz, &Ks[cur ^ 1][ch * 512]);
                gload_lds16(Vb + (size_t)rt * NS + kv1 + cswz, &Vs[cur ^ 1][ch * 512]);
            }
        }
        bool act[2];
        act[0] = (kv0 <= rbv[0] + 15);
        act[1] = true;
        // ---- swapped QK^T: sc = S^T (K frags shared across rowsets) ----
        f32x4 sc[2][4];
#pragma unroll
        for (int rs = 0; rs < 2; ++rs)
            if (act[rs])
#pragma unroll
                for (int ct = 0; ct < 4; ++ct) sc[rs][ct] = z;
#pragma unroll
        for (int kc = 0; kc < 2; ++kc) {
            bf16x8 kf[4];
#pragma unroll
            for (int ct = 0; ct < 4; ++ct) {
                const int rt = ct * 16 + l15;
                kf[ct] = *(const bf16x8*)&Ks[cur][rt * 64 + ((kc * 32 + lg * 8) ^ ((rt & 7) << 3))];
            }
#pragma unroll
            for (int rs = 0; rs < 2; ++rs)
                if (act[rs])
#pragma unroll
                    for (int ct = 0; ct < 4; ++ct)
                        sc[rs][ct] = __builtin_amdgcn_mfma_f32_16x16x32_bf16(kf[ct], qf[rs][kc], sc[rs][ct], 0, 0, 0);
        }
        // ---- in-lane softmax + pack, per rowset ----
        bf16x8 pb[2][2];
#pragma unroll
        for (int rs = 0; rs < 2; ++rs) {
            if (!act[rs]) continue;
            const int rbase = rbv[rs];
            const int qrow = rbase + l15;
            const bool needmask = (kv0 + 63 > rbase);
            if (needmask) {
#pragma unroll
                for (int ct = 0; ct < 4; ++ct)
#pragma unroll
                    for (int j = 0; j < 4; ++j) {
                        const int kvg = kv0 + ((ct >> 1) << 5) + lg * 8 + ((ct & 1) << 2) + j;
                        if (kvg > qrow) sc[rs][ct][j] = -1e30f;
                    }
            }
            // row max: in-lane tree over 16 regs, then 2 shfl across lg replicas
            float t0 = fmaxf(fmaxf(sc[rs][0][0], sc[rs][0][1]), fmaxf(sc[rs][0][2], sc[rs][0][3]));
            float t1 = fmaxf(fmaxf(sc[rs][1][0], sc[rs][1][1]), fmaxf(sc[rs][1][2], sc[rs][1][3]));
            float t2 = fmaxf(fmaxf(sc[rs][2][0], sc[rs][2][1]), fmaxf(sc[rs][2][2], sc[rs][2][3]));
            float t3 = fmaxf(fmaxf(sc[rs][3][0], sc[rs][3][1]), fmaxf(sc[rs][3][2], sc[rs][3][3]));
            float mt = fmaxf(fmaxf(t0, t1), fmaxf(t2, t3));
            mt = fmaxf(mt, __shfl_xor(mt, 16, 64));
            mt = fmaxf(mt, __shfl_xor(mt, 32, 64));
            float alpha = 1.0f;
            if (!__all(mt - m[rs] <= 8.0f)) {           // defer-max (T13)
                const float mn = fmaxf(m[rs], mt);
                alpha = __expf(m[rs] - mn);
                m[rs] = mn;
#pragma unroll
                for (int ct = 0; ct < 4; ++ct)
#pragma unroll
                    for (int j = 0; j < 4; ++j) oacc[rs][ct][j] *= alpha;
            }
            float ps = 0.f;
#pragma unroll
            for (int ct = 0; ct < 4; ++ct)
#pragma unroll
                for (int j = 0; j < 4; ++j) {
                    const float e = __expf(sc[rs][ct][j] - m[rs]);
                    sc[rs][ct][j] = e;
                    ps += e;
                }
            ps += __shfl_xor(ps, 16, 64);
            ps += __shfl_xor(ps, 32, 64);
            lsum[rs] = lsum[rs] * alpha + ps;
            // pack P B-fragments: pb[kc] = kv {kc*32+lg*8 .. +7} — all in-lane
#pragma unroll
            for (int kc = 0; kc < 2; ++kc) {
                bf16x8 pk;
                pk[0] = (__bf16)sc[rs][2 * kc][0];     pk[1] = (__bf16)sc[rs][2 * kc][1];
                pk[2] = (__bf16)sc[rs][2 * kc][2];     pk[3] = (__bf16)sc[rs][2 * kc][3];
                pk[4] = (__bf16)sc[rs][2 * kc + 1][0]; pk[5] = (__bf16)sc[rs][2 * kc + 1][1];
                pk[6] = (__bf16)sc[rs][2 * kc + 1][2]; pk[7] = (__bf16)sc[rs][2 * kc + 1][3];
                pb[rs][kc] = pk;
            }
        }
        // ---- PV: oacc(O^T) += V^T-frag (A) x P-frag (B) ----
#pragma unroll
        for (int kc = 0; kc < 2; ++kc) {
            bf16x8 vf[4];
#pragma unroll
            for (int ct = 0; ct < 4; ++ct) {
                const int rt = ct * 16 + l15;
                vf[ct] = *(const bf16x8*)&Vs[cur][rt * 64 + ((kc * 32 + lg * 8) ^ ((rt & 7) << 3))];
            }
#pragma unroll
            for (int rs = 0; rs < 2; ++rs) {
                if (!act[rs]) continue;
#pragma unroll
                for (int ct = 0; ct < 4; ++ct)
                    oacc[rs][ct] = __builtin_amdgcn_mfma_f32_16x16x32_bf16(vf[ct], pb[rs][kc], oacc[rs][ct], 0, 0, 0);
            }
        }
        __syncthreads();
    }
    // ---- epilogue: O[q][h*64 + d], d = ct*16 + lg*4 + j, q = rbase + l15 ----
#pragma unroll
    for (int rs = 0; rs < 2; ++rs) {
        const float rl = 1.0f / lsum[rs];
        const size_t rowoff = (size_t)(b * NS + rbv[rs] + l15) * NDM + h * 64 + lg * 4;
#pragma unroll
        for (int ct = 0; ct < 4; ++ct) {
            bf16x4 ov;
#pragma unroll
            for (int j = 0; j < 4; ++j) ov[j] = (__bf16)(oacc[rs][ct][j] * rl);
            *(bf16x4*)&O[rowoff + ct * 16] = ov;
        }
    }
}

// ---------------- launch ----------------
extern "C" void kernel_launch(void* const* d_in, const int* in_sizes, int n_in,
                              void* d_out, int out_size, void* d_ws, size_t ws_size,
                              hipStream_t stream) {
    const float* x  = (const float*)d_in[0];
    const float* Qw = (const float*)d_in[1];
    const float* Kw = (const float*)d_in[2];
    const float* Vw = (const float*)d_in[3];
    const float* Ow = (const float*)d_in[4];
    const int*   tp = (const int*)d_in[5];
    float* out = (float*)d_out;

    char* ws = (char*)d_ws;
    size_t off = 0;
    auto alloc = [&](size_t bytes) -> void* {
        void* p = ws + off;
        off += (bytes + 255) & ~(size_t)255;
        return p;
    };
    __bf16* xb   = (__bf16*)alloc((size_t)4096 * 1024 * 2);
    __bf16* wqkv = (__bf16*)alloc((size_t)3072 * 1024 * 2);
    __bf16* owb  = (__bf16*)alloc((size_t)1024 * 1024 * 2);
    __bf16* qkv  = (__bf16*)alloc((size_t)4096 * 3072 * 2);
    __bf16* qr   = (__bf16*)alloc((size_t)32 * 2048 * 64 * 2);
    __bf16* kr   = (__bf16*)alloc((size_t)32 * 2048 * 64 * 2);
    __bf16* vt   = (__bf16*)alloc((size_t)32 * 64 * 2048 * 2);
    __bf16* ob   = (__bf16*)alloc((size_t)4096 * 1024 * 2);

    cvt_f32_bf16<<<4096, 256, 0, stream>>>(x, xb, 4096 * 1024 / 4);
    cvt_weights<<<dim3(1024, 4), 256, 0, stream>>>(Qw, Kw, Vw, Ow, wqkv, owb);

    gemm_bt128<__bf16><<<dim3(3072 / 128, 4096 / 128), 256, 0, stream>>>(
        xb, wqkv, qkv, 1024, 1024, 1024, 3072);
    rope_kernel<<<4096, 512, 0, stream>>>(qkv, tp, qr, kr);
    vtrans<<<dim3(NS / 64, NB * NH), 256, 0, stream>>>(qkv, vt);
    attn4<<<dim3(512), 256, 0, stream>>>(qr, kr, vt, ob);
    gemm_bt128<float><<<dim3(1024 / 128, 4096 / 128), 256, 0, stream>>>(
        ob, owb, out, 1024, 1024, 1024, 1024);
}

// Round 5
// 122.876 us; speedup vs baseline: 3.2057x; 1.1769x over previous
//
#include <hip/hip_runtime.h>

#define NB 2
#define NS 2048
#define NDM 1024
#define NH 16
#define NDK 64

typedef unsigned int u32;
typedef u32 u32x4 __attribute__((ext_vector_type(4)));
typedef float f32x4 __attribute__((ext_vector_type(4)));
typedef __bf16 bf16x8 __attribute__((ext_vector_type(8)));
typedef __bf16 bf16x4 __attribute__((ext_vector_type(4)));
typedef __bf16 bf16x2 __attribute__((ext_vector_type(2)));

__device__ __forceinline__ void gload_lds16(const __bf16* g, __bf16* l) {
    __builtin_amdgcn_global_load_lds(
        (const __attribute__((address_space(1))) unsigned int*)(g),
        (__attribute__((address_space(3))) unsigned int*)(l), 16, 0, 0);
}

// ---------------- fp32 -> bf16 cast (x input) ----------------
__global__ __launch_bounds__(256) void cvt_f32_bf16(const float* __restrict__ src,
                                                    __bf16* __restrict__ dst, int n4) {
    int i = blockIdx.x * blockDim.x + threadIdx.x;
    if (i >= n4) return;
    f32x4 v = *(const f32x4*)(src + (size_t)i * 4);
    bf16x4 o;
    o[0] = (__bf16)v[0]; o[1] = (__bf16)v[1]; o[2] = (__bf16)v[2]; o[3] = (__bf16)v[3];
    *(bf16x4*)(dst + (size_t)i * 4) = o;
}

// ---------------- all 4 weight casts in one launch ----------------
__global__ __launch_bounds__(256) void cvt_weights(const float* __restrict__ q,
                                                   const float* __restrict__ k,
                                                   const float* __restrict__ v,
                                                   const float* __restrict__ o,
                                                   __bf16* __restrict__ wqkv,
                                                   __bf16* __restrict__ owb) {
    const int seg = blockIdx.y;
    const float* src = (seg == 0) ? q : (seg == 1) ? k : (seg == 2) ? v : o;
    __bf16* dst = (seg == 3) ? owb : wqkv + (size_t)seg * 1024 * 1024;
    const int i = blockIdx.x * 256 + threadIdx.x;
    f32x4 vv = *(const f32x4*)(src + (size_t)i * 4);
    bf16x4 ov;
    ov[0] = (__bf16)vv[0]; ov[1] = (__bf16)vv[1]; ov[2] = (__bf16)vv[2]; ov[3] = (__bf16)vv[3];
    *(bf16x4*)(dst + (size_t)i * 4) = ov;
}

// ---------------- GEMM v2: 128x128 tile, BK=64, dbuf LDS, T3-min prefetch, T2 swizzle ----
// C[M,N] = A[M,K] * Bt[N,K]^T. LDS dest linear (gload_lds), source col pre-swizzled,
// ds_read addr XOR-swizzled with the same key (rule #21 both-sides).
template <typename TOUT>
__global__ __launch_bounds__(256) void gemm_bt128(const __bf16* __restrict__ A,
                                                  const __bf16* __restrict__ Bt,
                                                  TOUT* __restrict__ C,
                                                  int K, int lda, int ldb, int ldc) {
    __shared__ __bf16 As[2][128 * 64];
    __shared__ __bf16 Bs[2][128 * 64];
    const int tid = threadIdx.x;
    const int lane = tid & 63, w = tid >> 6;
    const int wr = w >> 1, wc = w & 1;
    const int l15 = lane & 15, lg = lane >> 4;
    const int m0 = blockIdx.y * 128, n0 = blockIdx.x * 128;
    const int crow = lane >> 3;                   // row-in-chunk 0..7
    const int csw = ((lane & 7) ^ crow) * 8;      // inverse-swizzled source col (elements)

    f32x4 acc[4][4];
    const f32x4 z = {0.f, 0.f, 0.f, 0.f};
#pragma unroll
    for (int i = 0; i < 4; ++i)
#pragma unroll
        for (int jx = 0; jx < 4; ++jx) acc[i][jx] = z;

    auto stage = [&](int buf, int k0) {
#pragma unroll
        for (int ch = 0; ch < 4; ++ch) {
            const int cid = w * 4 + ch;
            const int ra = cid * 8 + crow;
            gload_lds16(&A[(size_t)(m0 + ra) * lda + k0 + csw], &As[buf][cid * 512]);
            gload_lds16(&Bt[(size_t)(n0 + ra) * ldb + k0 + csw], &Bs[buf][cid * 512]);
        }
    };

    stage(0, 0);
    __syncthreads();                               // drain tile-0 staging
    int cur = 0;
    for (int k0 = 0; k0 < K; k0 += 64) {
        if (k0 + 64 < K) stage(cur ^ 1, k0 + 64);  // prefetch next tile (in flight during MFMA)
#pragma unroll
        for (int kc = 0; kc < 2; ++kc) {
            bf16x8 af[4], bfv[4];
#pragma unroll
            for (int i = 0; i < 4; ++i) {
                const int ra = wr * 64 + i * 16 + l15;
                const int rb = wc * 64 + i * 16 + l15;
                af[i]  = *(const bf16x8*)&As[cur][ra * 64 + ((kc * 32 + lg * 8) ^ ((ra & 7) << 3))];
                bfv[i] = *(const bf16x8*)&Bs[cur][rb * 64 + ((kc * 32 + lg * 8) ^ ((rb & 7) << 3))];
            }
#pragma unroll
            for (int sm = 0; sm < 4; ++sm)
#pragma unroll
                for (int sn = 0; sn < 4; ++sn)
                    acc[sm][sn] = __builtin_amdgcn_mfma_f32_16x16x32_bf16(af[sm], bfv[sn], acc[sm][sn], 0, 0, 0);
        }
        __syncthreads();   // waves done reading cur; vmcnt(0) drain completes prefetch
        cur ^= 1;
    }
#pragma unroll
    for (int sm = 0; sm < 4; ++sm)
#pragma unroll
        for (int sn = 0; sn < 4; ++sn)
#pragma unroll
            for (int j = 0; j < 4; ++j) {
                const int row = m0 + wr * 64 + sm * 16 + lg * 4 + j;
                const int col = n0 + wc * 64 + sn * 16 + l15;
                C[(size_t)row * ldc + col] = (TOUT)acc[sm][sn][j];
            }
}

// ---------------- RoPE on Q and K halves (bf16 qkv in). Q pre-scaled by 1/8. ----------------
__global__ __launch_bounds__(512) void rope_kernel(const __bf16* __restrict__ qkv,
                                                   const int* __restrict__ tp,
                                                   __bf16* __restrict__ Qr,
                                                   __bf16* __restrict__ Kr) {
    const int row = blockIdx.x;           // b*S + s
    const int s = row & (NS - 1);
    const int b = row >> 11;
    const int t = threadIdx.x;            // 16 heads x 32 pairs
    const int h = t >> 5, jj = t & 31;
    const float pos = (float)tp[s];
    const float inv = exp2f(-0.41524101186092f * (float)jj);  // 10000^(-j/32)
    const float ang = pos * inv;
    float sn, cs;
    sincosf(ang, &sn, &cs);
    const __bf16* qp = qkv + (size_t)row * 3072 + h * 64 + 2 * jj;
    bf16x2 qv = *(const bf16x2*)qp;
    bf16x2 kv = *(const bf16x2*)(qp + 1024);
    const float q0 = (float)qv[0], q1 = (float)qv[1];
    const float k0 = (float)kv[0], k1 = (float)kv[1];
    const size_t o = ((size_t)(b * NH + h) * NS + s) * 64 + 2 * jj;
    bf16x2 qo, ko;
    qo[0] = (__bf16)((q0 * cs - q1 * sn) * 0.125f);
    qo[1] = (__bf16)((q0 * sn + q1 * cs) * 0.125f);
    ko[0] = (__bf16)(k0 * cs - k1 * sn); ko[1] = (__bf16)(k0 * sn + k1 * cs);
    *(bf16x2*)&Qr[o] = qo;
    *(bf16x2*)&Kr[o] = ko;
}

// ---------------- V transpose: qkv V-part (bf16) -> Vt [B*H, 64, S] ----------------
__global__ __launch_bounds__(256) void vtrans(const __bf16* __restrict__ qkv,
                                              __bf16* __restrict__ Vt) {
    const int bh = blockIdx.y;
    const int s0 = blockIdx.x * 64;
    const int b = bh >> 4, h = bh & 15;
    __shared__ __bf16 tile[64][72];
    const int t = threadIdx.x;
    const int sl = t >> 3, c8 = (t & 7) * 8;
#pragma unroll
    for (int pp = 0; pp < 2; ++pp) {
        const int srow = sl + pp * 32;
        bf16x8 v = *(const bf16x8*)&qkv[(size_t)(b * NS + s0 + srow) * 3072 + 2048 + h * 64 + c8];
        *(bf16x8*)&tile[srow][c8] = v;
    }
    __syncthreads();
    const int d = t >> 2;
#pragma unroll
    for (int pp = 0; pp < 2; ++pp) {
        const int vec = (t & 3) + pp * 4;
        bf16x8 o;
#pragma unroll
        for (int i = 0; i < 8; ++i) o[i] = tile[vec * 8 + i][d];
        *(bf16x8*)&Vt[((size_t)bh * 64 + d) * NS + s0 + vec * 8] = o;
    }
}

// K staging permutation: LDS slot rt holds K row kperm(rt) of the tile, so that
// after swapped QK^T (mfma(K,Q) -> S^T) each lane's registers hold exactly the
// contiguous-kv runs the PV B-fragment needs (zero cross-lane P exchange).
__device__ __forceinline__ int kperm(int rt) {
    const int ct = rt >> 4, rr = rt & 15;
    return ((rr >> 2) << 3) + ((ct >> 1) << 5) + ((ct & 1) << 2) + (rr & 3);
}

// ---------------- causal flash attention v4: swapped QK^T, in-lane softmax ----------------
__global__ __launch_bounds__(256) void attn4(const __bf16* __restrict__ Qr,
                                             const __bf16* __restrict__ Kr,
                                             const __bf16* __restrict__ Vt,
                                             __bf16* __restrict__ O) {
    const int lid = blockIdx.x;
    const int xcd = lid & 7, ix = lid >> 3;
    const int bh = xcd * 4 + (ix & 3);     // 4 heads per XCD -> K/V set 2MB < 4MB L2
    const int p  = ix >> 2;                // 0..15
    const int b = bh >> 4, h = bh & 15;
    const int tid = threadIdx.x;
    const int w = tid >> 6, lane = tid & 63;
    const int l15 = lane & 15, lg = lane >> 4;
    const __bf16* Qb = Qr + (size_t)bh * NS * 64;
    const __bf16* Kb = Kr + (size_t)bh * NS * 64;
    const __bf16* Vb = Vt + (size_t)bh * 64 * NS;

    __shared__ __bf16 Ks[2][64 * 64];
    __shared__ __bf16 Vs[2][64 * 64];

    const int rbv[2] = {p * 64 + w * 16, (31 - p) * 64 + w * 16};

    bf16x8 qf[2][2];
#pragma unroll
    for (int rs = 0; rs < 2; ++rs)
#pragma unroll
        for (int kc = 0; kc < 2; ++kc)
            qf[rs][kc] = *(const bf16x8*)(Qb + (size_t)(rbv[rs] + l15) * 64 + kc * 32 + lg * 8);

    f32x4 oacc[2][4];
    const f32x4 z = {0.f, 0.f, 0.f, 0.f};
#pragma unroll
    for (int rs = 0; rs < 2; ++rs)
#pragma unroll
        for (int ct = 0; ct < 4; ++ct) oacc[rs][ct] = z;
    float m[2], lsum[2];
#pragma unroll
    for (int rs = 0; rs < 2; ++rs) { m[rs] = -1e30f; lsum[rs] = 0.f; }

    const int crow = lane >> 3;
    const int cswz = ((lane & 7) ^ crow) * 8;

#pragma unroll
    for (int pp = 0; pp < 2; ++pp) {
        const int ch = w + pp * 4;
        const int rt = ch * 8 + crow;
        gload_lds16(Kb + (size_t)kperm(rt) * 64 + cswz, &Ks[0][ch * 512]);
        gload_lds16(Vb + (size_t)rt * NS + 0 + cswz, &Vs[0][ch * 512]);
    }
    __syncthreads();

    const int nt = 32 - p;
    for (int t = 0; t < nt; ++t) {
        const int cur = t & 1;
        const int kv0 = t << 6;
        if (t + 1 < nt) {
            const int kv1 = kv0 + 64;
#pragma unroll
            for (int pp = 0; pp < 2; ++pp) {
                const int ch = w + pp * 4;
                const int rt = ch * 8 + crow;
                gload_lds16(Kb + (size_t)(kv1 + kperm(rt)) * 64 + cswz, &Ks[cur ^ 1][ch * 512]);
                gload_lds16(Vb + (size_t)rt * NS + kv1 + cswz, &Vs[cur ^ 1][ch * 512]);
            }
        }
        bool act[2];
        act[0] = (kv0 <= rbv[0] + 15);
        act[1] = true;
        f32x4 sc[2][4];
#pragma unroll
        for (int rs = 0; rs < 2; ++rs)
            if (act[rs])
#pragma unroll
                for (int ct = 0; ct < 4; ++ct) sc[rs][ct] = z;
#pragma unroll
        for (int kc = 0; kc < 2; ++kc) {
            bf16x8 kf[4];
#pragma unroll
            for (int ct = 0; ct < 4; ++ct) {
                const int rt = ct * 16 + l15;
                kf[ct] = *(const bf16x8*)&Ks[cur][rt * 64 + ((kc * 32 + lg * 8) ^ ((rt & 7) << 3))];
            }
#pragma unroll
            for (int rs = 0; rs < 2; ++rs)
                if (act[rs])
#pragma unroll
                    for (int ct = 0; ct < 4; ++ct)
                        sc[rs][ct] = __builtin_amdgcn_mfma_f32_16x16x32_bf16(kf[ct], qf[rs][kc], sc[rs][ct], 0, 0, 0);
        }
        bf16x8 pb[2][2];
#pragma unroll
        for (int rs = 0; rs < 2; ++rs) {
            if (!act[rs]) continue;
            const int rbase = rbv[rs];
            const int qrow = rbase + l15;
            const bool needmask = (kv0 + 63 > rbase);
            if (needmask) {
#pragma unroll
                for (int ct = 0; ct < 4; ++ct)
#pragma unroll
                    for (int j = 0; j < 4; ++j) {
                        const int kvg = kv0 + ((ct >> 1) << 5) + lg * 8 + ((ct & 1) << 2) + j;
                        if (kvg > qrow) sc[rs][ct][j] = -1e30f;
                    }
            }
            float t0 = fmaxf(fmaxf(sc[rs][0][0], sc[rs][0][1]), fmaxf(sc[rs][0][2], sc[rs][0][3]));
            float t1 = fmaxf(fmaxf(sc[rs][1][0], sc[rs][1][1]), fmaxf(sc[rs][1][2], sc[rs][1][3]));
            float t2 = fmaxf(fmaxf(sc[rs][2][0], sc[rs][2][1]), fmaxf(sc[rs][2][2], sc[rs][2][3]));
            float t3 = fmaxf(fmaxf(sc[rs][3][0], sc[rs][3][1]), fmaxf(sc[rs][3][2], sc[rs][3][3]));
            float mt = fmaxf(fmaxf(t0, t1), fmaxf(t2, t3));
            mt = fmaxf(mt, __shfl_xor(mt, 16, 64));
            mt = fmaxf(mt, __shfl_xor(mt, 32, 64));
            float alpha = 1.0f;
            if (!__all(mt - m[rs] <= 8.0f)) {           // defer-max (T13)
                const float mn = fmaxf(m[rs], mt);
                alpha = __expf(m[rs] - mn);
                m[rs] = mn;
#pragma unroll
                for (int ct = 0; ct < 4; ++ct)
#pragma unroll
                    for (int j = 0; j < 4; ++j) oacc[rs][ct][j] *= alpha;
            }
            float ps = 0.f;
#pragma unroll
            for (int ct = 0; ct < 4; ++ct)
#pragma unroll
                for (int j = 0; j < 4; ++j) {
                    const float e = __expf(sc[rs][ct][j] - m[rs]);
                    sc[rs][ct][j] = e;
                    ps += e;
                }
            ps += __shfl_xor(ps, 16, 64);
            ps += __shfl_xor(ps, 32, 64);
            lsum[rs] = lsum[rs] * alpha + ps;
#pragma unroll
            for (int kc = 0; kc < 2; ++kc) {
                bf16x8 pk;
                pk[0] = (__bf16)sc[rs][2 * kc][0];     pk[1] = (__bf16)sc[rs][2 * kc][1];
                pk[2] = (__bf16)sc[rs][2 * kc][2];     pk[3] = (__bf16)sc[rs][2 * kc][3];
                pk[4] = (__bf16)sc[rs][2 * kc + 1][0]; pk[5] = (__bf16)sc[rs][2 * kc + 1][1];
                pk[6] = (__bf16)sc[rs][2 * kc + 1][2]; pk[7] = (__bf16)sc[rs][2 * kc + 1][3];
                pb[rs][kc] = pk;
            }
        }
#pragma unroll
        for (int kc = 0; kc < 2; ++kc) {
            bf16x8 vf[4];
#pragma unroll
            for (int ct = 0; ct < 4; ++ct) {
                const int rt = ct * 16 + l15;
                vf[ct] = *(const bf16x8*)&Vs[cur][rt * 64 + ((kc * 32 + lg * 8) ^ ((rt & 7) << 3))];
            }
#pragma unroll
            for (int rs = 0; rs < 2; ++rs) {
                if (!act[rs]) continue;
#pragma unroll
                for (int ct = 0; ct < 4; ++ct)
                    oacc[rs][ct] = __builtin_amdgcn_mfma_f32_16x16x32_bf16(vf[ct], pb[rs][kc], oacc[rs][ct], 0, 0, 0);
            }
        }
        __syncthreads();
    }
#pragma unroll
    for (int rs = 0; rs < 2; ++rs) {
        const float rl = 1.0f / lsum[rs];
        const size_t rowoff = (size_t)(b * NS + rbv[rs] + l15) * NDM + h * 64 + lg * 4;
#pragma unroll
        for (int ct = 0; ct < 4; ++ct) {
            bf16x4 ov;
#pragma unroll
            for (int j = 0; j < 4; ++j) ov[j] = (__bf16)(oacc[rs][ct][j] * rl);
            *(bf16x4*)&O[rowoff + ct * 16] = ov;
        }
    }
}

// ---------------- launch ----------------
extern "C" void kernel_launch(void* const* d_in, const int* in_sizes, int n_in,
                              void* d_out, int out_size, void* d_ws, size_t ws_size,
                              hipStream_t stream) {
    const float* x  = (const float*)d_in[0];
    const float* Qw = (const float*)d_in[1];
    const float* Kw = (const float*)d_in[2];
    const float* Vw = (const float*)d_in[3];
    const float* Ow = (const float*)d_in[4];
    const int*   tp = (const int*)d_in[5];
    float* out = (float*)d_out;

    char* ws = (char*)d_ws;
    size_t off = 0;
    auto alloc = [&](size_t bytes) -> void* {
        void* p = ws + off;
        off += (bytes + 255) & ~(size_t)255;
        return p;
    };
    __bf16* xb   = (__bf16*)alloc((size_t)4096 * 1024 * 2);
    __bf16* wqkv = (__bf16*)alloc((size_t)3072 * 1024 * 2);
    __bf16* owb  = (__bf16*)alloc((size_t)1024 * 1024 * 2);
    __bf16* qkv  = (__bf16*)alloc((size_t)4096 * 3072 * 2);
    __bf16* qr   = (__bf16*)alloc((size_t)32 * 2048 * 64 * 2);
    __bf16* kr   = (__bf16*)alloc((size_t)32 * 2048 * 64 * 2);
    __bf16* vt   = (__bf16*)alloc((size_t)32 * 64 * 2048 * 2);
    __bf16* ob   = (__bf16*)alloc((size_t)4096 * 1024 * 2);

    cvt_f32_bf16<<<4096, 256, 0, stream>>>(x, xb, 4096 * 1024 / 4);
    cvt_weights<<<dim3(1024, 4), 256, 0, stream>>>(Qw, Kw, Vw, Ow, wqkv, owb);

    gemm_bt128<__bf16><<<dim3(3072 / 128, 4096 / 128), 256, 0, stream>>>(
        xb, wqkv, qkv, 1024, 1024, 1024, 3072);
    rope_kernel<<<4096, 512, 0, stream>>>(qkv, tp, qr, kr);
    vtrans<<<dim3(NS / 64, NB * NH), 256, 0, stream>>>(qkv, vt);
    attn4<<<dim3(512), 256, 0, stream>>>(qr, kr, vt, ob);
    gemm_bt128<float><<<dim3(1024 / 128, 4096 / 128), 256, 0, stream>>>(
        ob, owb, out, 1024, 1024, 1024, 1024);
}